// Round 4
// baseline (144.140 us; speedup 1.0000x reference)
//
#include <hip/hip_runtime.h>

#define B_SZ 256
#define L_SZ 2048
#define T_SZ 32
#define START_IDX 0
#define STOP_IDX 1

// split config: each wave runs TWO 64-step chains; 8 waves/block -> 16 chunks/block
#define CLEN 64
#define NSLOT 16          // tree slots per block
#define NMAT_SEQ 2        // block-matrices per sequence after in-block tree
#define NBLK_TOT (B_SZ * NMAT_SEQ)   // 512 blocks

// fallback (round-1) config
#define FB_NCH 16
#define FB_CLEN 128

// 6*ln2: fixed per-step 2^-6 scale folded into exp staging
#define SCALE_LN 4.1588830833596718565f

typedef __attribute__((ext_vector_type(8))) short bf16x8;
typedef __attribute__((ext_vector_type(4))) float f32x4;
typedef __attribute__((ext_vector_type(2))) float f32x2;

__device__ __forceinline__ unsigned fau(float f){ union{float f; unsigned u;} v; v.f=f; return v.u; }
__device__ __forceinline__ float uaf(unsigned u){ union{unsigned u; float f;} v; v.u=u; return v.f; }
__device__ __forceinline__ int pack_trunc(float lo, float hi){
  return (int)__builtin_amdgcn_perm(fau(hi), fau(lo), 0x07060302u);
}
__device__ __forceinline__ bf16x8 frag_of(const int* p){
  union{ int i[4]; bf16x8 v; } u;
  u.i[0]=p[0]; u.i[1]=p[1]; u.i[2]=p[2]; u.i[3]=p[3];
  return u.v;
}

__global__ void zero_kernel(float* out){ if(threadIdx.x==0) out[0]=0.f; }

// ---- 32x32 matrix product Q = L x Rt (L: R-layout [x*32+m], Rt: T-layout [y*32+m]).
__device__ __forceinline__ int mat_prod(const unsigned short* L, const unsigned short* Rt,
                                        unsigned short* dst, bool writeT, int lane)
{
  const int g = lane >> 4, c16 = lane & 15;
  const int ko = 8*g;
  bf16x8 A0 = *(const bf16x8*)(L  + (c16*T_SZ      + ko));
  bf16x8 A1 = *(const bf16x8*)(L  + ((16+c16)*T_SZ + ko));
  bf16x8 B0 = *(const bf16x8*)(Rt + (c16*T_SZ      + ko));
  bf16x8 B1 = *(const bf16x8*)(Rt + ((16+c16)*T_SZ + ko));
  const f32x4 zf = {0.f,0.f,0.f,0.f};
  f32x4 q00 = __builtin_amdgcn_mfma_f32_16x16x32_bf16(A0, B0, zf, 0,0,0);
  f32x4 q01 = __builtin_amdgcn_mfma_f32_16x16x32_bf16(A0, B1, zf, 0,0,0);
  f32x4 q10 = __builtin_amdgcn_mfma_f32_16x16x32_bf16(A1, B0, zf, 0,0,0);
  f32x4 q11 = __builtin_amdgcn_mfma_f32_16x16x32_bf16(A1, B1, zf, 0,0,0);

  unsigned mb = (unsigned)__builtin_amdgcn_readfirstlane((int)fau(q00[0]));
  int e = (int)((mb>>23)&255u) - 127;
  float r = uaf((unsigned)(127-e)<<23);
  #pragma unroll
  for (int i=0;i<4;++i){ q00[i]*=r; q01[i]*=r; q10[i]*=r; q11[i]*=r; }

  if (!writeT){
    #pragma unroll
    for (int reg=0; reg<4; ++reg){
      int x0 = 4*g + reg, x1 = 16 + 4*g + reg;
      dst[x0*T_SZ + c16]      = (unsigned short)(fau(q00[reg])>>16);
      dst[x0*T_SZ + 16 + c16] = (unsigned short)(fau(q01[reg])>>16);
      dst[x1*T_SZ + c16]      = (unsigned short)(fau(q10[reg])>>16);
      dst[x1*T_SZ + 16 + c16] = (unsigned short)(fau(q11[reg])>>16);
    }
  } else {
    #pragma unroll
    for (int rp=0; rp<2; ++rp){
      int xb0 = 4*g + 2*rp, xb1 = 16 + 4*g + 2*rp;
      *(int*)&dst[c16*T_SZ + xb0]        = pack_trunc(q00[2*rp], q00[2*rp+1]);
      *(int*)&dst[(16+c16)*T_SZ + xb0]   = pack_trunc(q01[2*rp], q01[2*rp+1]);
      *(int*)&dst[c16*T_SZ + xb1]        = pack_trunc(q10[2*rp], q10[2*rp+1]);
      *(int*)&dst[(16+c16)*T_SZ + xb1]   = pack_trunc(q11[2*rp], q11[2*rp+1]);
    }
  }
  return e;
}

// ---- cold path: one chain with arbitrary mask (never taken in the benchmark)
__device__ void run_chain_cold(const float* fpt, unsigned long long mbits,
                               float* s_dc, int lane, int g,
                               const int* a0, const int* a1, int* b0, int* b1)
{
  const f32x4 zf = {0.f,0.f,0.f,0.f};
  float fq[4];
  #pragma unroll
  for (int i=1; i<=4; ++i) fq[i&3] = fpt[i*64 + lane];
  s_dc[lane] = __expf(fpt[lane] - SCALE_LN);

  for (int p=0; p<32; ++p){
    if (p < 31){
      s_dc[((p+1)&1)*64 + lane] = __expf(fq[(p+1)&3] - SCALE_LN);
      int np = p+5; if (np > 31) np = 31;
      fq[(p+1)&3] = fpt[np*64 + lane];
    }
    const float* dbase = &s_dc[(p&1)*64];
    #pragma unroll
    for (int h=0; h<2; ++h){
      int t = 2*p + h;
      if ((mbits >> t) & 1ull){
        f32x4 c00 = __builtin_amdgcn_mfma_f32_16x16x32_bf16(frag_of(a0), frag_of(b0), zf, 0,0,0);
        f32x4 c01 = __builtin_amdgcn_mfma_f32_16x16x32_bf16(frag_of(a0), frag_of(b1), zf, 0,0,0);
        f32x4 c10 = __builtin_amdgcn_mfma_f32_16x16x32_bf16(frag_of(a1), frag_of(b0), zf, 0,0,0);
        f32x4 c11 = __builtin_amdgcn_mfma_f32_16x16x32_bf16(frag_of(a1), frag_of(b1), zf, 0,0,0);

        const float4* dv = (const float4*)(dbase + h*32);
        float4 dl = dv[2*g], dh2 = dv[2*g+1];
        float f0=dl.x, f1=dl.y, f2=dl.z, f3=dl.w;
        float f4=dh2.x, f5=dh2.y, f6=dh2.z, f7=dh2.w;

        c00[0]*=f0; c00[1]*=f1; c00[2]*=f2; c00[3]*=f3;
        c01[0]*=f0; c01[1]*=f1; c01[2]*=f2; c01[3]*=f3;
        c10[0]*=f4; c10[1]*=f5; c10[2]*=f6; c10[3]*=f7;
        c11[0]*=f4; c11[1]*=f5; c11[2]*=f6; c11[3]*=f7;

        b0[0]=pack_trunc(c00[0],c00[1]); b0[1]=pack_trunc(c00[2],c00[3]);
        b0[2]=pack_trunc(c10[0],c10[1]); b0[3]=pack_trunc(c10[2],c10[3]);
        b1[0]=pack_trunc(c01[0],c01[1]); b1[1]=pack_trunc(c01[2],c01[3]);
        b1[2]=pack_trunc(c11[0],c11[1]); b1[3]=pack_trunc(c11[2],c11[3]);
      }
    }
  }
}

// ===================== kernel 1: 2 chains/wave + in-block 16->1 tree =====================
__global__ __launch_bounds__(512, 4) void crf_chunk_kernel(
    const float* __restrict__ efeats, const float* __restrict__ mask,
    const int* __restrict__ tgt, const float* __restrict__ trans,
    unsigned short* __restrict__ wsM, int* __restrict__ wsE,
    float* __restrict__ wsG, float* __restrict__ wsL)
{
  __shared__ float s_trans[T_SZ*T_SZ];
  __shared__ float s_d[8][2][128];                    // [wave][chain][dbuf*64+lane]
  __shared__ unsigned short s_tree[NSLOT][T_SZ*T_SZ]; // 32 KiB
  __shared__ int   s_et[NSLOT];
  __shared__ float s_gd[8], s_ml[8];

  const int tid  = threadIdx.x;
  const int w    = tid >> 6;
  const int lane = tid & 63;
  const int g    = lane >> 4;
  const int c16  = lane & 15;

  const int b  = blockIdx.x >> 1;
  const int q  = blockIdx.x & 1;
  const int cA = q*16 + w;        // slot w
  const int cB = q*16 + 8 + w;    // slot 8+w
  const int l0A = cA * CLEN, l0B = cB * CLEN;

  s_trans[tid]     = trans[tid];
  s_trans[tid+512] = trans[tid+512];
  __syncthreads();

  // ---- constant A-frags (sigma-relabeled rows), shared by both chains
  int a0[4], a1[4];
  #pragma unroll
  for (int I=0; I<2; ++I){
    int row = 8*(c16>>2) + 4*I + (c16&3);
    float e[8];
    #pragma unroll
    for (int j=0;j<8;++j) e[j] = __expf(s_trans[row*T_SZ + 8*g + j]);
    int* dst = I ? a1 : a0;
    #pragma unroll
    for (int p=0;p<4;++p) dst[p] = pack_trunc(e[2*p], e[2*p+1]);
  }

  // ---- B-frags = identity, both chains
  int bA0[4], bA1[4], bB0[4], bB1[4];
  #pragma unroll
  for (int p=0;p<4;++p){
    int s0 = 8*g + 2*p, s1 = s0+1;
    unsigned lo = (s0==c16)?0x3f80u:0u, hi = (s1==c16)?0x3f80u:0u;
    bA0[p] = (int)(lo | (hi<<16)); bB0[p] = bA0[p];
    lo = (s0==16+c16)?0x3f80u:0u; hi = (s1==16+c16)?0x3f80u:0u;
    bA1[p] = (int)(lo | (hi<<16)); bB1[p] = bA1[p];
  }

  const long fbase = ((long)b * L_SZ) * T_SZ;

  // ---- per-chain mask/tgt
  float mvA = mask[b*L_SZ + l0A + lane];
  float mvB = mask[b*L_SZ + l0B + lane];
  int   tcA = tgt [b*L_SZ + l0A + lane];
  int   tcB = tgt [b*L_SZ + l0B + lane];
  int   tpA = (l0A + lane == 0) ? START_IDX : tgt[b*L_SZ + l0A + lane - 1];
  int   tpB = tgt[b*L_SZ + l0B + lane - 1];

  // gold + length, lane-parallel (both chains)
  float emA = efeats[fbase + (long)(l0A+lane)*T_SZ + tcA];
  float emB = efeats[fbase + (long)(l0B+lane)*T_SZ + tcB];
  float gl = ((mvA > 0.f) ? (s_trans[tcA*T_SZ + tpA] + emA) : 0.f)
           + ((mvB > 0.f) ? (s_trans[tcB*T_SZ + tpB] + emB) : 0.f);
  float ml = mvA + mvB;
  #pragma unroll
  for (int off=32; off>0; off>>=1){ gl += __shfl_xor(gl, off, 64); ml += __shfl_xor(ml, off, 64); }

  unsigned long long mbA = __ballot(mvA > 0.f);
  unsigned long long mbB = __ballot(mvB > 0.f);

  const float* fptA = efeats + fbase + (long)l0A*T_SZ;
  const float* fptB = efeats + fbase + (long)l0B*T_SZ;
  float* s_dA = &s_d[w][0][0];
  float* s_dB = &s_d[w][1][0];

  const f32x4 zf = {0.f,0.f,0.f,0.f};

  if ((mbA & mbB) == ~0ull){
    // ================= HOT: both chains dense, interleaved straight-line =================
    float fqA[4], fqB[4];
    #pragma unroll
    for (int i=1; i<=4; ++i){ fqA[i&3] = fptA[i*64 + lane]; fqB[i&3] = fptB[i*64 + lane]; }
    s_dA[lane] = __expf(fptA[lane] - SCALE_LN);
    s_dB[lane] = __expf(fptB[lane] - SCALE_LN);

    #pragma unroll 2
    for (int p=0; p<32; ++p){
      s_dA[((p+1)&1)*64 + lane] = __expf(fqA[(p+1)&3] - SCALE_LN);
      s_dB[((p+1)&1)*64 + lane] = __expf(fqB[(p+1)&3] - SCALE_LN);
      int np = p+5; np = (np>31)?31:np;
      fqA[(p+1)&3] = fptA[np*64 + lane];
      fqB[(p+1)&3] = fptB[np*64 + lane];
      const float* dbA = &s_dA[(p&1)*64];
      const float* dbB = &s_dB[(p&1)*64];
      #pragma unroll
      for (int h=0; h<2; ++h){
        f32x4 cA00 = __builtin_amdgcn_mfma_f32_16x16x32_bf16(frag_of(a0), frag_of(bA0), zf, 0,0,0);
        f32x4 cA01 = __builtin_amdgcn_mfma_f32_16x16x32_bf16(frag_of(a0), frag_of(bA1), zf, 0,0,0);
        f32x4 cA10 = __builtin_amdgcn_mfma_f32_16x16x32_bf16(frag_of(a1), frag_of(bA0), zf, 0,0,0);
        f32x4 cA11 = __builtin_amdgcn_mfma_f32_16x16x32_bf16(frag_of(a1), frag_of(bA1), zf, 0,0,0);
        f32x4 cB00 = __builtin_amdgcn_mfma_f32_16x16x32_bf16(frag_of(a0), frag_of(bB0), zf, 0,0,0);
        f32x4 cB01 = __builtin_amdgcn_mfma_f32_16x16x32_bf16(frag_of(a0), frag_of(bB1), zf, 0,0,0);
        f32x4 cB10 = __builtin_amdgcn_mfma_f32_16x16x32_bf16(frag_of(a1), frag_of(bB0), zf, 0,0,0);
        f32x4 cB11 = __builtin_amdgcn_mfma_f32_16x16x32_bf16(frag_of(a1), frag_of(bB1), zf, 0,0,0);

        const float4* dvA = (const float4*)(dbA + h*32);
        const float4* dvB = (const float4*)(dbB + h*32);
        float4 al = dvA[2*g], ah = dvA[2*g+1];
        float4 bl = dvB[2*g], bh = dvB[2*g+1];

        f32x2 pA0 = {cA00[0],cA00[1]}; pA0 *= (f32x2){al.x,al.y};
        f32x2 pA1 = {cA00[2],cA00[3]}; pA1 *= (f32x2){al.z,al.w};
        f32x2 pA2 = {cA01[0],cA01[1]}; pA2 *= (f32x2){al.x,al.y};
        f32x2 pA3 = {cA01[2],cA01[3]}; pA3 *= (f32x2){al.z,al.w};
        f32x2 pA4 = {cA10[0],cA10[1]}; pA4 *= (f32x2){ah.x,ah.y};
        f32x2 pA5 = {cA10[2],cA10[3]}; pA5 *= (f32x2){ah.z,ah.w};
        f32x2 pA6 = {cA11[0],cA11[1]}; pA6 *= (f32x2){ah.x,ah.y};
        f32x2 pA7 = {cA11[2],cA11[3]}; pA7 *= (f32x2){ah.z,ah.w};

        bA0[0]=pack_trunc(pA0[0],pA0[1]); bA0[1]=pack_trunc(pA1[0],pA1[1]);
        bA0[2]=pack_trunc(pA4[0],pA4[1]); bA0[3]=pack_trunc(pA5[0],pA5[1]);
        bA1[0]=pack_trunc(pA2[0],pA2[1]); bA1[1]=pack_trunc(pA3[0],pA3[1]);
        bA1[2]=pack_trunc(pA6[0],pA6[1]); bA1[3]=pack_trunc(pA7[0],pA7[1]);

        f32x2 pB0 = {cB00[0],cB00[1]}; pB0 *= (f32x2){bl.x,bl.y};
        f32x2 pB1 = {cB00[2],cB00[3]}; pB1 *= (f32x2){bl.z,bl.w};
        f32x2 pB2 = {cB01[0],cB01[1]}; pB2 *= (f32x2){bl.x,bl.y};
        f32x2 pB3 = {cB01[2],cB01[3]}; pB3 *= (f32x2){bl.z,bl.w};
        f32x2 pB4 = {cB10[0],cB10[1]}; pB4 *= (f32x2){bh.x,bh.y};
        f32x2 pB5 = {cB10[2],cB10[3]}; pB5 *= (f32x2){bh.z,bh.w};
        f32x2 pB6 = {cB11[0],cB11[1]}; pB6 *= (f32x2){bh.x,bh.y};
        f32x2 pB7 = {cB11[2],cB11[3]}; pB7 *= (f32x2){bh.z,bh.w};

        bB0[0]=pack_trunc(pB0[0],pB0[1]); bB0[1]=pack_trunc(pB1[0],pB1[1]);
        bB0[2]=pack_trunc(pB4[0],pB4[1]); bB0[3]=pack_trunc(pB5[0],pB5[1]);
        bB1[0]=pack_trunc(pB2[0],pB2[1]); bB1[1]=pack_trunc(pB3[0],pB3[1]);
        bB1[2]=pack_trunc(pB6[0],pB6[1]); bB1[3]=pack_trunc(pB7[0],pB7[1]);
      }
    }
  } else {
    // ================= COLD: arbitrary masks, chains sequential =================
    run_chain_cold(fptA, mbA, s_dA, lane, g, a0, a1, bA0, bA1);
    run_chain_cold(fptB, mbB, s_dB, lane, g, a0, a1, bB0, bB1);
  }

  // ---- write both chunk matrices to tree slots (slot parity -> R or T layout)
  {
    unsigned short* SA = &s_tree[w][0];
    unsigned short* SB = &s_tree[8+w][0];
    if ((w & 1) == 0){
      #pragma unroll
      for (int p=0;p<4;++p){
        int s = 8*g + 2*p;
        *(int*)&SA[c16*T_SZ + s]      = bA0[p];
        *(int*)&SA[(16+c16)*T_SZ + s] = bA1[p];
        *(int*)&SB[c16*T_SZ + s]      = bB0[p];
        *(int*)&SB[(16+c16)*T_SZ + s] = bB1[p];
      }
    } else {
      #pragma unroll
      for (int p=0;p<4;++p){
        int s = 8*g + 2*p;
        SA[s*T_SZ + c16]          = (unsigned short)(bA0[p] & 0xffff);
        SA[(s+1)*T_SZ + c16]      = (unsigned short)(((unsigned)bA0[p])>>16);
        SA[s*T_SZ + 16 + c16]     = (unsigned short)(bA1[p] & 0xffff);
        SA[(s+1)*T_SZ + 16 + c16] = (unsigned short)(((unsigned)bA1[p])>>16);
        SB[s*T_SZ + c16]          = (unsigned short)(bB0[p] & 0xffff);
        SB[(s+1)*T_SZ + c16]      = (unsigned short)(((unsigned)bB0[p])>>16);
        SB[s*T_SZ + 16 + c16]     = (unsigned short)(bB1[p] & 0xffff);
        SB[(s+1)*T_SZ + 16 + c16] = (unsigned short)(((unsigned)bB1[p])>>16);
      }
    }
  }
  if (lane==0){
    s_et[w]   = 6 * __popcll(mbA);
    s_et[8+w] = 6 * __popcll(mbB);
    s_gd[w] = gl; s_ml[w] = ml;
  }
  __syncthreads();

  // ---- tree: 16 -> 1
  if (w < 8){
    int e = mat_prod(&s_tree[2*w][0], &s_tree[2*w+1][0], &s_tree[2*w][0], (w&1)!=0, lane);
    if (lane==0) s_et[2*w] = s_et[2*w] + s_et[2*w+1] + e;
  }
  __syncthreads();
  if (w < 4){
    int e = mat_prod(&s_tree[4*w][0], &s_tree[4*w+2][0], &s_tree[4*w][0], (w&1)!=0, lane);
    if (lane==0) s_et[4*w] = s_et[4*w] + s_et[4*w+2] + e;
  }
  __syncthreads();
  if (w < 2){
    int e = mat_prod(&s_tree[8*w][0], &s_tree[8*w+4][0], &s_tree[8*w][0], (w&1)!=0, lane);
    if (lane==0) s_et[8*w] = s_et[8*w] + s_et[8*w+4] + e;
  }
  __syncthreads();
  if (w == 0){
    int e = mat_prod(&s_tree[0][0], &s_tree[8][0], &s_tree[0][0], false, lane);
    if (lane==0) s_et[0] = s_et[0] + s_et[8] + e;
  }
  __syncthreads();

  // ---- export block matrix (R layout) + scalars
  const int bid = blockIdx.x;
  if (tid < 512)
    ((int*)(wsM + (long)bid*(T_SZ*T_SZ)))[tid] = ((const int*)&s_tree[0][0])[tid];
  if (tid == 0){
    wsE[bid] = s_et[0];
    float gs=0.f, ls=0.f;
    #pragma unroll
    for (int i=0;i<8;++i){ gs += s_gd[i]; ls += s_ml[i]; }
    wsG[bid] = gs; wsL[bid] = ls;
  }
}

// ===================== kernel 2: combine 2 block-matrices per sequence =====================
__global__ __launch_bounds__(64) void crf_combine_kernel(
    const unsigned short* __restrict__ wsM, const int* __restrict__ wsE,
    const float* __restrict__ wsG, const float* __restrict__ wsL,
    const int* __restrict__ tgt, const float* __restrict__ trans,
    float* __restrict__ out)
{
  __shared__ unsigned short sM[NMAT_SEQ*T_SZ*T_SZ];   // 4 KiB
  __shared__ float s_v[T_SZ];

  const int tid = threadIdx.x;
  const int b   = blockIdx.x;

  const uint4* src = (const uint4*)(wsM + (long)b*NMAT_SEQ*T_SZ*T_SZ);
  #pragma unroll
  for (int i=0;i<4;++i) ((uint4*)sM)[tid + i*64] = src[tid + i*64];
  __syncthreads();

  const int s = tid & 31;
  float v = (s==START_IDX)?1.f:0.f;
  int E = 0;
  #pragma unroll
  for (int j=0; j<NMAT_SEQ; ++j){
    if (tid < 32) s_v[s] = v;
    __syncthreads();
    const unsigned short* M = &sM[j*T_SZ*T_SZ];
    float u = 0.f;
    #pragma unroll 8
    for (int x=0; x<T_SZ; ++x){
      float mv = uaf(((unsigned)M[x*T_SZ + s])<<16);
      u = fmaf(mv, s_v[x], u);
    }
    unsigned ub = (unsigned)__builtin_amdgcn_readfirstlane((int)fau(u));
    int eu = (int)((ub>>23)&255u)-127;
    E += wsE[b*NMAT_SEQ + j] + eu;
    v = u * uaf((unsigned)(127-eu)<<23);
    __syncthreads();
  }
  float term = v * __expf(trans[STOP_IDX*T_SZ + s]);
  #pragma unroll
  for (int off=16; off>0; off>>=1) term += __shfl_xor(term, off, 32);
  float fwd = (float)E * 0.69314718055994530942f + __logf(term);

  if (tid == 0){
    float gp = 0.f, lp = 0.f;
    #pragma unroll
    for (int j=0;j<NMAT_SEQ;++j){ gp += wsG[b*NMAT_SEQ+j]; lp += wsL[b*NMAT_SEQ+j]; }
    int len = (int)lp;
    int last_tag = (len==0)? START_IDX : tgt[b*L_SZ + len-1];
    float goldT = gp + trans[STOP_IDX*T_SZ + last_tag];
    atomicAdd(out, (fwd - goldT) * (1.0f/B_SZ));
  }
}

// ===================== fallback: round-1 single kernel (no workspace) =====================
__global__ __launch_bounds__(1024) void crf_loss_kernel(
    const float* __restrict__ efeats, const float* __restrict__ mask,
    const int* __restrict__ tgt, const float* __restrict__ trans,
    float* __restrict__ out)
{
  __shared__ float s_trans[T_SZ*T_SZ];
  __shared__ float s_d[FB_NCH][T_SZ];
  __shared__ unsigned short s_M[FB_NCH][T_SZ*T_SZ];
  __shared__ int   s_es[FB_NCH];
  __shared__ float s_gd[FB_NCH];
  __shared__ float s_mlv[FB_NCH];

  const int tid  = threadIdx.x;
  const int b    = blockIdx.x;
  const int w    = tid >> 6;
  const int lane = tid & 63;
  const int g    = lane >> 4;
  const int c16  = lane & 15;
  const int i32  = lane & 31;

  s_trans[tid] = trans[tid];
  __syncthreads();

  int a0[4], a1[4];
  #pragma unroll
  for (int I=0; I<2; ++I){
    int row = 8*(c16>>2) + 4*I + (c16&3);
    float e[8];
    #pragma unroll
    for (int j=0;j<8;++j) e[j] = __expf(s_trans[row*T_SZ + 8*g + j]);
    int* dst = I ? a1 : a0;
    #pragma unroll
    for (int p=0;p<4;++p) dst[p] = pack_trunc(e[2*p], e[2*p+1]);
  }

  int b0[4], b1[4];
  #pragma unroll
  for (int p=0;p<4;++p){
    int s0 = 8*g + 2*p, s1 = s0+1;
    unsigned lo = (s0==c16)?0x3f80u:0u, hi = (s1==c16)?0x3f80u:0u;
    b0[p] = (int)(lo | (hi<<16));
    lo = (s0==16+c16)?0x3f80u:0u; hi = (s1==16+c16)?0x3f80u:0u;
    b1[p] = (int)(lo | (hi<<16));
  }

  const int l0 = w * FB_CLEN;
  const long fbase = ((long)b * L_SZ) * T_SZ;

  float fqv[4];
  #pragma unroll
  for (int i=0;i<4;++i) fqv[i] = efeats[fbase + (long)(l0+i)*T_SZ + i32];

  int   tA = tgt [b*L_SZ + l0 + lane];
  int   tB = tgt [b*L_SZ + l0 + 64 + lane];
  float mA = mask[b*L_SZ + l0 + lane];
  float mB = mask[b*L_SZ + l0 + 64 + lane];
  int prev = (l0==0) ? START_IDX : tgt[b*L_SZ + l0 - 1];

  int esum = 0;
  float gold = 0.f, mlen = 0.f;
  const f32x4 zf = {0.f,0.f,0.f,0.f};

  #pragma unroll 4
  for (int t=0; t<FB_CLEN; ++t){
    float fcur = fqv[t&3];
    int lpf = l0 + t + 4; lpf = (lpf < L_SZ) ? lpf : (L_SZ-1);
    fqv[t&3] = efeats[fbase + (long)lpf*T_SZ + i32];

    float mk  = uaf((unsigned)__builtin_amdgcn_readlane((int)fau((t<64)?mA:mB), t&63));
    int   cur = __builtin_amdgcn_readlane((t<64)?tA:tB, t&63);
    mlen += mk;

    if (mk > 0.f){
      if (lane < 32) s_d[w][lane] = __expf(fcur);

      f32x4 c00 = __builtin_amdgcn_mfma_f32_16x16x32_bf16(frag_of(a0), frag_of(b0), zf, 0,0,0);
      f32x4 c01 = __builtin_amdgcn_mfma_f32_16x16x32_bf16(frag_of(a0), frag_of(b1), zf, 0,0,0);
      f32x4 c10 = __builtin_amdgcn_mfma_f32_16x16x32_bf16(frag_of(a1), frag_of(b0), zf, 0,0,0);
      f32x4 c11 = __builtin_amdgcn_mfma_f32_16x16x32_bf16(frag_of(a1), frag_of(b1), zf, 0,0,0);

      const float4* dv = (const float4*)(&s_d[w][0]);
      float4 dl = dv[2*g], dh = dv[2*g+1];
      float f0=dl.x, f1=dl.y, f2=dl.z, f3=dl.w;
      float f4=dh.x, f5=dh.y, f6=dh.z, f7=dh.w;

      float m00 = c00[0]*f0;
      unsigned mb = (unsigned)__builtin_amdgcn_readfirstlane((int)fau(m00));
      int e = (int)((mb>>23)&255u) - 127;
      esum += e;
      float r = uaf((unsigned)(127-e)<<23);
      f0*=r; f1*=r; f2*=r; f3*=r; f4*=r; f5*=r; f6*=r; f7*=r;

      c00[0]*=f0; c00[1]*=f1; c00[2]*=f2; c00[3]*=f3;
      c01[0]*=f0; c01[1]*=f1; c01[2]*=f2; c01[3]*=f3;
      c10[0]*=f4; c10[1]*=f5; c10[2]*=f6; c10[3]*=f7;
      c11[0]*=f4; c11[1]*=f5; c11[2]*=f6; c11[3]*=f7;

      b0[0]=pack_trunc(c00[0],c00[1]); b0[1]=pack_trunc(c00[2],c00[3]);
      b0[2]=pack_trunc(c10[0],c10[1]); b0[3]=pack_trunc(c10[2],c10[3]);
      b1[0]=pack_trunc(c01[0],c01[1]); b1[1]=pack_trunc(c01[2],c01[3]);
      b1[2]=pack_trunc(c11[0],c11[1]); b1[3]=pack_trunc(c11[2],c11[3]);

      float tp   = s_trans[cur*T_SZ + prev];
      float emit = uaf((unsigned)__builtin_amdgcn_readlane((int)fau(fcur), cur));
      gold += tp + emit;
    }
    prev = cur;
  }

  #pragma unroll
  for (int p=0;p<4;++p){
    int s = 8*g + 2*p;
    *(int*)((char*)(&s_M[w][0]) + (((long)(c16   )*T_SZ + s) * 2)) = b0[p];
    *(int*)((char*)(&s_M[w][0]) + (((long)(16+c16)*T_SZ + s) * 2)) = b1[p];
  }
  if (lane==0){ s_es[w]=esum; s_gd[w]=gold; s_mlv[w]=mlen; }
  __syncthreads();

  if (w==0){
    int s = i32;
    float v = (s==START_IDX)?1.f:0.f;
    int E = 0;
    for (int c=0;c<FB_NCH;++c){
      float u=0.f;
      #pragma unroll 8
      for (int k=0;k<T_SZ;++k){
        float mv = uaf(((unsigned)s_M[c][k*T_SZ + s])<<16);
        float vk = uaf((unsigned)__builtin_amdgcn_readlane((int)fau(v), k));
        u = fmaf(mv, vk, u);
      }
      unsigned ub = (unsigned)__builtin_amdgcn_readfirstlane((int)fau(u));
      int eu = (int)((ub>>23)&255u)-127;
      E += s_es[c] + eu;
      v = u * uaf((unsigned)(127-eu)<<23);
    }
    float term = v * __expf(s_trans[STOP_IDX*T_SZ + s]);
    #pragma unroll
    for (int off=16; off>0; off>>=1) term += __shfl_xor(term, off, 32);
    float fwd = (float)E * 0.69314718055994530942f + __logf(term);

    float gp = (s<FB_NCH)? s_gd[s] : 0.f;
    float lp = (s<FB_NCH)? s_mlv[s] : 0.f;
    #pragma unroll
    for (int off=16; off>0; off>>=1){ gp += __shfl_xor(gp, off, 32); lp += __shfl_xor(lp, off, 32); }
    int len = (int)lp;
    int last_tag = (len==0)? START_IDX : tgt[b*L_SZ + (len-1)];
    float goldT = gp + s_trans[STOP_IDX*T_SZ + last_tag];
    if (tid==0) atomicAdd(out, (fwd - goldT) * (1.0f/B_SZ));
  }
}

extern "C" void kernel_launch(void* const* d_in, const int* in_sizes, int n_in,
                              void* d_out, int out_size, void* d_ws, size_t ws_size,
                              hipStream_t stream)
{
  const float* efeats = (const float*)d_in[0];
  const float* mask   = (const float*)d_in[1];
  const int*   tgt    = (const int*)d_in[2];
  const float* trans  = (const float*)d_in[3];
  float* out = (float*)d_out;

  const size_t needM = (size_t)NBLK_TOT * T_SZ * T_SZ * 2;   // 1 MiB
  const size_t need  = needM + (size_t)NBLK_TOT * 12;

  zero_kernel<<<dim3(1), dim3(64), 0, stream>>>(out);

  if (ws_size >= need){
    unsigned short* wsM = (unsigned short*)d_ws;
    char* p = (char*)d_ws + needM;
    int*   wsE = (int*)p;
    float* wsG = (float*)(p + (size_t)NBLK_TOT*4);
    float* wsL = (float*)(p + (size_t)NBLK_TOT*8);
    crf_chunk_kernel<<<dim3(NBLK_TOT), dim3(512), 0, stream>>>(
        efeats, mask, tgt, trans, wsM, wsE, wsG, wsL);
    crf_combine_kernel<<<dim3(B_SZ), dim3(64), 0, stream>>>(
        wsM, wsE, wsG, wsL, tgt, trans, out);
  } else {
    crf_loss_kernel<<<dim3(B_SZ), dim3(1024), 0, stream>>>(efeats, mask, tgt, trans, out);
  }
}

// Round 5
// 141.334 us; speedup vs baseline: 1.0198x; 1.0198x over previous
//
#include <hip/hip_runtime.h>

#define B_SZ 256
#define L_SZ 2048
#define T_SZ 32
#define START_IDX 0
#define STOP_IDX 1

// split config: 1 chain/wave, CLEN=128; 8 waves/block -> 8 chunks/block; tree 8->1
#define CLEN 128
#define NPAIR 64          // CLEN/2
#define NSLOT 8
#define NMAT_SEQ 2        // block-matrices per sequence
#define NBLK_TOT (B_SZ * NMAT_SEQ)   // 512 blocks = exactly 2 blocks/CU

// fallback (round-1) config
#define FB_NCH 16
#define FB_CLEN 128

// 6*ln2: fixed per-step 2^-6 scale folded into exp staging
#define SCALE_LN 4.1588830833596718565f

typedef __attribute__((ext_vector_type(8))) short bf16x8;
typedef __attribute__((ext_vector_type(4))) float f32x4;
typedef __attribute__((ext_vector_type(2))) float f32x2;

__device__ __forceinline__ unsigned fau(float f){ union{float f; unsigned u;} v; v.f=f; return v.u; }
__device__ __forceinline__ float uaf(unsigned u){ union{unsigned u; float f;} v; v.u=u; return v.f; }
__device__ __forceinline__ int pack_trunc(float lo, float hi){
  return (int)__builtin_amdgcn_perm(fau(hi), fau(lo), 0x07060302u);
}
__device__ __forceinline__ bf16x8 frag_of(const int* p){
  union{ int i[4]; bf16x8 v; } u;
  u.i[0]=p[0]; u.i[1]=p[1]; u.i[2]=p[2]; u.i[3]=p[3];
  return u.v;
}

// ---- 4x MFMA 16x16x32 bf16, VGPR-class forced via "v" constraints (no AGPR copies).
// s_nop 1: VALU-write -> MFMA-read-A/B hazard guard.
// s_nop 7 x2: MFMA-write-D -> VALU-read hazard guard (16 cy, covers 4-pass XDL).
__device__ __forceinline__ void mfma4(bf16x8 A0, bf16x8 A1, bf16x8 B0, bf16x8 B1,
                                      f32x4& c00, f32x4& c01, f32x4& c10, f32x4& c11)
{
  const f32x4 z = {0.f,0.f,0.f,0.f};
  asm("s_nop 1\n\t"
      "v_mfma_f32_16x16x32_bf16 %0, %4, %5, %8\n\t"
      "v_mfma_f32_16x16x32_bf16 %1, %4, %6, %8\n\t"
      "v_mfma_f32_16x16x32_bf16 %2, %7, %5, %8\n\t"
      "v_mfma_f32_16x16x32_bf16 %3, %7, %6, %8\n\t"
      "s_nop 7\n\t"
      "s_nop 7"
      : "=&v"(c00), "=&v"(c01), "=&v"(c10), "=&v"(c11)
      : "v"(A0), "v"(B0), "v"(B1), "v"(A1), "v"(z));
}

__global__ void zero_kernel(float* out){ if(threadIdx.x==0) out[0]=0.f; }

// ---- 32x32 matrix product Q = compose(late, early) using standard frag layouts.
// L (early) in R-layout [origin*32+state], Rt (late) in T-layout [state*32+origin].
__device__ __forceinline__ int mat_prod(const unsigned short* L, const unsigned short* Rt,
                                        unsigned short* dst, bool writeT, int lane)
{
  const int g = lane >> 4, c16 = lane & 15;
  const int ko = 8*g;
  bf16x8 A0 = *(const bf16x8*)(L  + (c16*T_SZ      + ko));
  bf16x8 A1 = *(const bf16x8*)(L  + ((16+c16)*T_SZ + ko));
  bf16x8 B0 = *(const bf16x8*)(Rt + (c16*T_SZ      + ko));
  bf16x8 B1 = *(const bf16x8*)(Rt + ((16+c16)*T_SZ + ko));
  f32x4 q00,q01,q10,q11;
  mfma4(A0, A1, B0, B1, q00, q01, q10, q11);

  unsigned mb = (unsigned)__builtin_amdgcn_readfirstlane((int)fau(q00[0]));
  int e = (int)((mb>>23)&255u) - 127;
  float r = uaf((unsigned)(127-e)<<23);
  #pragma unroll
  for (int i=0;i<4;++i){ q00[i]*=r; q01[i]*=r; q10[i]*=r; q11[i]*=r; }

  if (!writeT){
    #pragma unroll
    for (int reg=0; reg<4; ++reg){
      int x0 = 4*g + reg, x1 = 16 + 4*g + reg;
      dst[x0*T_SZ + c16]      = (unsigned short)(fau(q00[reg])>>16);
      dst[x0*T_SZ + 16 + c16] = (unsigned short)(fau(q01[reg])>>16);
      dst[x1*T_SZ + c16]      = (unsigned short)(fau(q10[reg])>>16);
      dst[x1*T_SZ + 16 + c16] = (unsigned short)(fau(q11[reg])>>16);
    }
  } else {
    #pragma unroll
    for (int rp=0; rp<2; ++rp){
      int xb0 = 4*g + 2*rp, xb1 = 16 + 4*g + 2*rp;
      *(int*)&dst[c16*T_SZ + xb0]        = pack_trunc(q00[2*rp], q00[2*rp+1]);
      *(int*)&dst[(16+c16)*T_SZ + xb0]   = pack_trunc(q01[2*rp], q01[2*rp+1]);
      *(int*)&dst[c16*T_SZ + xb1]        = pack_trunc(q10[2*rp], q10[2*rp+1]);
      *(int*)&dst[(16+c16)*T_SZ + xb1]   = pack_trunc(q11[2*rp], q11[2*rp+1]);
    }
  }
  return e;
}

// ===================== kernel 1: per-chunk transfer matrices + in-block 8->1 tree =====================
__global__ __launch_bounds__(512, 4) void crf_chunk_kernel(
    const float* __restrict__ efeats, const float* __restrict__ mask,
    const int* __restrict__ tgt, const float* __restrict__ trans,
    unsigned short* __restrict__ wsM, int* __restrict__ wsE,
    float* __restrict__ wsG, float* __restrict__ wsL)
{
  __shared__ float s_trans[T_SZ*T_SZ];
  __shared__ float s_d[8][128];                      // per-wave double-buffered exp(feat) pairs
  __shared__ unsigned short s_tree[NSLOT][T_SZ*T_SZ];// 16 KiB
  __shared__ int   s_et[NSLOT];
  __shared__ float s_gd[8], s_ml[8];

  const int tid  = threadIdx.x;
  const int w    = tid >> 6;
  const int lane = tid & 63;
  const int g    = lane >> 4;
  const int c16  = lane & 15;

  const int b  = blockIdx.x >> 1;
  const int q  = blockIdx.x & 1;
  const int c  = q*NSLOT + w;
  const int l0 = c * CLEN;

  s_trans[tid]     = trans[tid];
  s_trans[tid+512] = trans[tid+512];
  __syncthreads();

  // ---- constant A-frags (sigma-relabeled rows so C-layout == next B-layout lane-identically)
  bf16x8 A0f, A1f;
  {
    int a0i[4], a1i[4];
    #pragma unroll
    for (int I=0; I<2; ++I){
      int row = 8*(c16>>2) + 4*I + (c16&3);
      float e[8];
      #pragma unroll
      for (int j=0;j<8;++j) e[j] = __expf(s_trans[row*T_SZ + 8*g + j]);
      int* dst = I ? a1i : a0i;
      #pragma unroll
      for (int p=0;p<4;++p) dst[p] = pack_trunc(e[2*p], e[2*p+1]);
    }
    A0f = frag_of(a0i); A1f = frag_of(a1i);
  }

  // ---- B-frags = identity
  int b0[4], b1[4];
  #pragma unroll
  for (int p=0;p<4;++p){
    int s0 = 8*g + 2*p, s1 = s0+1;
    unsigned lo = (s0==c16)?0x3f80u:0u, hi = (s1==c16)?0x3f80u:0u;
    b0[p] = (int)(lo | (hi<<16));
    lo = (s0==16+c16)?0x3f80u:0u; hi = (s1==16+c16)?0x3f80u:0u;
    b1[p] = (int)(lo | (hi<<16));
  }

  const long fbase = ((long)b * L_SZ) * T_SZ;
  const int  mbase = b*L_SZ + l0;

  // ---- per-lane per-step data: lane covers steps (lane) and (64+lane)
  float mA = mask[mbase + lane];
  float mB = mask[mbase + 64 + lane];
  int   tA = tgt [mbase + lane];
  int   tB = tgt [mbase + 64 + lane];
  int   tpA = (l0 + lane == 0) ? START_IDX : tgt[mbase + lane - 1];
  int   tpB = tgt[mbase + 64 + lane - 1];

  // gold + length, lane-parallel
  float emA = efeats[fbase + (long)(l0+lane)*T_SZ + tA];
  float emB = efeats[fbase + (long)(l0+64+lane)*T_SZ + tB];
  float gl = ((mA > 0.f) ? (s_trans[tA*T_SZ + tpA] + emA) : 0.f)
           + ((mB > 0.f) ? (s_trans[tB*T_SZ + tpB] + emB) : 0.f);
  float ml = mA + mB;
  #pragma unroll
  for (int off=32; off>0; off>>=1){ gl += __shfl_xor(gl, off, 64); ml += __shfl_xor(ml, off, 64); }

  unsigned long long mb0 = __ballot(mA > 0.f);
  unsigned long long mb1 = __ballot(mB > 0.f);

  const float* fpt = efeats + fbase + (long)l0*T_SZ;
  float* s_dw = &s_d[w][0];

  // prefetch pairs 1..4; stage pair 0
  float fq[4];
  #pragma unroll
  for (int i=1; i<=4; ++i) fq[i&3] = fpt[i*64 + lane];
  s_dw[lane] = __expf(fpt[lane] - SCALE_LN);

  if ((mb0 & mb1) == ~0ull){
    // ================= HOT: dense mask, branchless =================
    #pragma unroll 4
    for (int p=0; p<NPAIR; ++p){
      s_dw[((p+1)&1)*64 + lane] = __expf(fq[(p+1)&3] - SCALE_LN);
      int np = p+5; np = (np > NPAIR-1) ? (NPAIR-1) : np;
      fq[(p+1)&3] = fpt[np*64 + lane];
      const float* dbase = &s_dw[(p&1)*64];
      #pragma unroll
      for (int h=0; h<2; ++h){
        f32x4 c00,c01,c10,c11;
        mfma4(A0f, A1f, frag_of(b0), frag_of(b1), c00,c01,c10,c11);

        const float4* dv = (const float4*)(dbase + h*32);
        float4 dl = dv[2*g], dh2 = dv[2*g+1];
        f32x2 q0={c00[0],c00[1]}; q0 *= (f32x2){dl.x,dl.y};
        f32x2 q1={c00[2],c00[3]}; q1 *= (f32x2){dl.z,dl.w};
        f32x2 q2={c01[0],c01[1]}; q2 *= (f32x2){dl.x,dl.y};
        f32x2 q3={c01[2],c01[3]}; q3 *= (f32x2){dl.z,dl.w};
        f32x2 q4={c10[0],c10[1]}; q4 *= (f32x2){dh2.x,dh2.y};
        f32x2 q5={c10[2],c10[3]}; q5 *= (f32x2){dh2.z,dh2.w};
        f32x2 q6={c11[0],c11[1]}; q6 *= (f32x2){dh2.x,dh2.y};
        f32x2 q7={c11[2],c11[3]}; q7 *= (f32x2){dh2.z,dh2.w};

        b0[0]=pack_trunc(q0[0],q0[1]); b0[1]=pack_trunc(q1[0],q1[1]);
        b0[2]=pack_trunc(q4[0],q4[1]); b0[3]=pack_trunc(q5[0],q5[1]);
        b1[0]=pack_trunc(q2[0],q2[1]); b1[1]=pack_trunc(q3[0],q3[1]);
        b1[2]=pack_trunc(q6[0],q6[1]); b1[3]=pack_trunc(q7[0],q7[1]);
      }
    }
  } else {
    // ================= COLD: arbitrary mask =================
    for (int p=0; p<NPAIR; ++p){
      s_dw[((p+1)&1)*64 + lane] = __expf(fq[(p+1)&3] - SCALE_LN);
      int np = p+5; if (np > NPAIR-1) np = NPAIR-1;
      fq[(p+1)&3] = fpt[np*64 + lane];
      const float* dbase = &s_dw[(p&1)*64];
      #pragma unroll
      for (int h=0; h<2; ++h){
        int t = 2*p + h;
        unsigned long long bit = (t < 64) ? (mb0 >> t) : (mb1 >> (t-64));
        if (bit & 1ull){
          f32x4 c00,c01,c10,c11;
          mfma4(A0f, A1f, frag_of(b0), frag_of(b1), c00,c01,c10,c11);

          const float4* dv = (const float4*)(dbase + h*32);
          float4 dl = dv[2*g], dh2 = dv[2*g+1];
          float f0=dl.x, f1=dl.y, f2=dl.z, f3=dl.w;
          float f4=dh2.x, f5=dh2.y, f6=dh2.z, f7=dh2.w;

          c00[0]*=f0; c00[1]*=f1; c00[2]*=f2; c00[3]*=f3;
          c01[0]*=f0; c01[1]*=f1; c01[2]*=f2; c01[3]*=f3;
          c10[0]*=f4; c10[1]*=f5; c10[2]*=f6; c10[3]*=f7;
          c11[0]*=f4; c11[1]*=f5; c11[2]*=f6; c11[3]*=f7;

          b0[0]=pack_trunc(c00[0],c00[1]); b0[1]=pack_trunc(c00[2],c00[3]);
          b0[2]=pack_trunc(c10[0],c10[1]); b0[3]=pack_trunc(c10[2],c10[3]);
          b1[0]=pack_trunc(c01[0],c01[1]); b1[1]=pack_trunc(c01[2],c01[3]);
          b1[2]=pack_trunc(c11[0],c11[1]); b1[3]=pack_trunc(c11[2],c11[3]);
        }
      }
    }
  }

  // ---- write chunk matrix to tree slot (even w: R layout, odd w: T layout)
  {
    unsigned short* S = &s_tree[w][0];
    if ((w & 1) == 0){
      #pragma unroll
      for (int p=0;p<4;++p){
        int s = 8*g + 2*p;
        *(int*)&S[c16*T_SZ + s]      = b0[p];
        *(int*)&S[(16+c16)*T_SZ + s] = b1[p];
      }
    } else {
      #pragma unroll
      for (int p=0;p<4;++p){
        int s = 8*g + 2*p;
        S[s*T_SZ + c16]          = (unsigned short)(b0[p] & 0xffff);
        S[(s+1)*T_SZ + c16]      = (unsigned short)(((unsigned)b0[p])>>16);
        S[s*T_SZ + 16 + c16]     = (unsigned short)(b1[p] & 0xffff);
        S[(s+1)*T_SZ + 16 + c16] = (unsigned short)(((unsigned)b1[p])>>16);
      }
    }
  }
  if (lane==0){
    s_et[w] = 6 * (__popcll(mb0) + __popcll(mb1));
    s_gd[w] = gl; s_ml[w] = ml;
  }
  __syncthreads();

  // ---- tree: 8 -> 1
  if (w < 4){
    int e = mat_prod(&s_tree[2*w][0], &s_tree[2*w+1][0], &s_tree[2*w][0], (w&1)!=0, lane);
    if (lane==0) s_et[2*w] = s_et[2*w] + s_et[2*w+1] + e;
  }
  __syncthreads();
  if (w < 2){
    int e = mat_prod(&s_tree[4*w][0], &s_tree[4*w+2][0], &s_tree[4*w][0], (w&1)!=0, lane);
    if (lane==0) s_et[4*w] = s_et[4*w] + s_et[4*w+2] + e;
  }
  __syncthreads();
  if (w == 0){
    int e = mat_prod(&s_tree[0][0], &s_tree[4][0], &s_tree[0][0], false, lane);
    if (lane==0) s_et[0] = s_et[0] + s_et[4] + e;
  }
  __syncthreads();

  // ---- export block matrix (R layout) + scalars
  const int bid = blockIdx.x;
  ((int*)(wsM + (long)bid*(T_SZ*T_SZ)))[tid] = ((const int*)&s_tree[0][0])[tid];
  if (tid == 0){
    wsE[bid] = s_et[0];
    float gs=0.f, ls=0.f;
    #pragma unroll
    for (int i=0;i<8;++i){ gs += s_gd[i]; ls += s_ml[i]; }
    wsG[bid] = gs; wsL[bid] = ls;
  }
}

// ===================== kernel 2: combine 2 block-matrices per sequence =====================
__global__ __launch_bounds__(64) void crf_combine_kernel(
    const unsigned short* __restrict__ wsM, const int* __restrict__ wsE,
    const float* __restrict__ wsG, const float* __restrict__ wsL,
    const int* __restrict__ tgt, const float* __restrict__ trans,
    float* __restrict__ out)
{
  __shared__ unsigned short sM[NMAT_SEQ*T_SZ*T_SZ];   // 4 KiB
  __shared__ float s_v[T_SZ];

  const int tid = threadIdx.x;
  const int b   = blockIdx.x;

  const uint4* src = (const uint4*)(wsM + (long)b*NMAT_SEQ*T_SZ*T_SZ);
  #pragma unroll
  for (int i=0;i<4;++i) ((uint4*)sM)[tid + i*64] = src[tid + i*64];
  __syncthreads();

  const int s = tid & 31;
  float v = (s==START_IDX)?1.f:0.f;
  int E = 0;
  #pragma unroll
  for (int j=0; j<NMAT_SEQ; ++j){
    if (tid < 32) s_v[s] = v;
    __syncthreads();
    const unsigned short* M = &sM[j*T_SZ*T_SZ];
    float u = 0.f;
    #pragma unroll 8
    for (int x=0; x<T_SZ; ++x){
      float mv = uaf(((unsigned)M[x*T_SZ + s])<<16);
      u = fmaf(mv, s_v[x], u);
    }
    unsigned ub = (unsigned)__builtin_amdgcn_readfirstlane((int)fau(u));
    int eu = (int)((ub>>23)&255u)-127;
    E += wsE[b*NMAT_SEQ + j] + eu;
    v = u * uaf((unsigned)(127-eu)<<23);
    __syncthreads();
  }
  float term = v * __expf(trans[STOP_IDX*T_SZ + s]);
  #pragma unroll
  for (int off=16; off>0; off>>=1) term += __shfl_xor(term, off, 32);
  float fwd = (float)E * 0.69314718055994530942f + __logf(term);

  if (tid == 0){
    float gp = 0.f, lp = 0.f;
    #pragma unroll
    for (int j=0;j<NMAT_SEQ;++j){ gp += wsG[b*NMAT_SEQ+j]; lp += wsL[b*NMAT_SEQ+j]; }
    int len = (int)lp;
    int last_tag = (len==0)? START_IDX : tgt[b*L_SZ + len-1];
    float goldT = gp + trans[STOP_IDX*T_SZ + last_tag];
    atomicAdd(out, (fwd - goldT) * (1.0f/B_SZ));
  }
}

// ===================== fallback: round-1 single kernel (no workspace) =====================
__global__ __launch_bounds__(1024) void crf_loss_kernel(
    const float* __restrict__ efeats, const float* __restrict__ mask,
    const int* __restrict__ tgt, const float* __restrict__ trans,
    float* __restrict__ out)
{
  __shared__ float s_trans[T_SZ*T_SZ];
  __shared__ float s_d[FB_NCH][T_SZ];
  __shared__ unsigned short s_M[FB_NCH][T_SZ*T_SZ];
  __shared__ int   s_es[FB_NCH];
  __shared__ float s_gd[FB_NCH];
  __shared__ float s_mlv[FB_NCH];

  const int tid  = threadIdx.x;
  const int b    = blockIdx.x;
  const int w    = tid >> 6;
  const int lane = tid & 63;
  const int g    = lane >> 4;
  const int c16  = lane & 15;
  const int i32  = lane & 31;

  s_trans[tid] = trans[tid];
  __syncthreads();

  int a0[4], a1[4];
  #pragma unroll
  for (int I=0; I<2; ++I){
    int row = 8*(c16>>2) + 4*I + (c16&3);
    float e[8];
    #pragma unroll
    for (int j=0;j<8;++j) e[j] = __expf(s_trans[row*T_SZ + 8*g + j]);
    int* dst = I ? a1 : a0;
    #pragma unroll
    for (int p=0;p<4;++p) dst[p] = pack_trunc(e[2*p], e[2*p+1]);
  }

  int b0[4], b1[4];
  #pragma unroll
  for (int p=0;p<4;++p){
    int s0 = 8*g + 2*p, s1 = s0+1;
    unsigned lo = (s0==c16)?0x3f80u:0u, hi = (s1==c16)?0x3f80u:0u;
    b0[p] = (int)(lo | (hi<<16));
    lo = (s0==16+c16)?0x3f80u:0u; hi = (s1==16+c16)?0x3f80u:0u;
    b1[p] = (int)(lo | (hi<<16));
  }

  const int l0 = w * FB_CLEN;
  const long fbase = ((long)b * L_SZ) * T_SZ;

  float fqv[4];
  #pragma unroll
  for (int i=0;i<4;++i) fqv[i] = efeats[fbase + (long)(l0+i)*T_SZ + i32];

  int   tA = tgt [b*L_SZ + l0 + lane];
  int   tB = tgt [b*L_SZ + l0 + 64 + lane];
  float mA = mask[b*L_SZ + l0 + lane];
  float mB = mask[b*L_SZ + l0 + 64 + lane];
  int prev = (l0==0) ? START_IDX : tgt[b*L_SZ + l0 - 1];

  int esum = 0;
  float gold = 0.f, mlen = 0.f;
  const f32x4 zf = {0.f,0.f,0.f,0.f};

  #pragma unroll 4
  for (int t=0; t<FB_CLEN; ++t){
    float fcur = fqv[t&3];
    int lpf = l0 + t + 4; lpf = (lpf < L_SZ) ? lpf : (L_SZ-1);
    fqv[t&3] = efeats[fbase + (long)lpf*T_SZ + i32];

    float mk  = uaf((unsigned)__builtin_amdgcn_readlane((int)fau((t<64)?mA:mB), t&63));
    int   cur = __builtin_amdgcn_readlane((t<64)?tA:tB, t&63);
    mlen += mk;

    if (mk > 0.f){
      if (lane < 32) s_d[w][lane] = __expf(fcur);

      f32x4 c00 = __builtin_amdgcn_mfma_f32_16x16x32_bf16(frag_of(a0), frag_of(b0), zf, 0,0,0);
      f32x4 c01 = __builtin_amdgcn_mfma_f32_16x16x32_bf16(frag_of(a0), frag_of(b1), zf, 0,0,0);
      f32x4 c10 = __builtin_amdgcn_mfma_f32_16x16x32_bf16(frag_of(a1), frag_of(b0), zf, 0,0,0);
      f32x4 c11 = __builtin_amdgcn_mfma_f32_16x16x32_bf16(frag_of(a1), frag_of(b1), zf, 0,0,0);

      const float4* dv = (const float4*)(&s_d[w][0]);
      float4 dl = dv[2*g], dh = dv[2*g+1];
      float f0=dl.x, f1=dl.y, f2=dl.z, f3=dl.w;
      float f4=dh.x, f5=dh.y, f6=dh.z, f7=dh.w;

      float m00 = c00[0]*f0;
      unsigned mb = (unsigned)__builtin_amdgcn_readfirstlane((int)fau(m00));
      int e = (int)((mb>>23)&255u) - 127;
      esum += e;
      float r = uaf((unsigned)(127-e)<<23);
      f0*=r; f1*=r; f2*=r; f3*=r; f4*=r; f5*=r; f6*=r; f7*=r;

      c00[0]*=f0; c00[1]*=f1; c00[2]*=f2; c00[3]*=f3;
      c01[0]*=f0; c01[1]*=f1; c01[2]*=f2; c01[3]*=f3;
      c10[0]*=f4; c10[1]*=f5; c10[2]*=f6; c10[3]*=f7;
      c11[0]*=f4; c11[1]*=f5; c11[2]*=f6; c11[3]*=f7;

      b0[0]=pack_trunc(c00[0],c00[1]); b0[1]=pack_trunc(c00[2],c00[3]);
      b0[2]=pack_trunc(c10[0],c10[1]); b0[3]=pack_trunc(c10[2],c10[3]);
      b1[0]=pack_trunc(c01[0],c01[1]); b1[1]=pack_trunc(c01[2],c01[3]);
      b1[2]=pack_trunc(c11[0],c11[1]); b1[3]=pack_trunc(c11[2],c11[3]);

      float tp   = s_trans[cur*T_SZ + prev];
      float emit = uaf((unsigned)__builtin_amdgcn_readlane((int)fau(fcur), cur));
      gold += tp + emit;
    }
    prev = cur;
  }

  #pragma unroll
  for (int p=0;p<4;++p){
    int s = 8*g + 2*p;
    *(int*)((char*)(&s_M[w][0]) + (((long)(c16   )*T_SZ + s) * 2)) = b0[p];
    *(int*)((char*)(&s_M[w][0]) + (((long)(16+c16)*T_SZ + s) * 2)) = b1[p];
  }
  if (lane==0){ s_es[w]=esum; s_gd[w]=gold; s_mlv[w]=mlen; }
  __syncthreads();

  if (w==0){
    int s = i32;
    float v = (s==START_IDX)?1.f:0.f;
    int E = 0;
    for (int c=0;c<FB_NCH;++c){
      float u=0.f;
      #pragma unroll 8
      for (int k=0;k<T_SZ;++k){
        float mv = uaf(((unsigned)s_M[c][k*T_SZ + s])<<16);
        float vk = uaf((unsigned)__builtin_amdgcn_readlane((int)fau(v), k));
        u = fmaf(mv, vk, u);
      }
      unsigned ub = (unsigned)__builtin_amdgcn_readfirstlane((int)fau(u));
      int eu = (int)((ub>>23)&255u)-127;
      E += s_es[c] + eu;
      v = u * uaf((unsigned)(127-eu)<<23);
    }
    float term = v * __expf(s_trans[STOP_IDX*T_SZ + s]);
    #pragma unroll
    for (int off=16; off>0; off>>=1) term += __shfl_xor(term, off, 32);
    float fwd = (float)E * 0.69314718055994530942f + __logf(term);

    float gp = (s<FB_NCH)? s_gd[s] : 0.f;
    float lp = (s<FB_NCH)? s_mlv[s] : 0.f;
    #pragma unroll
    for (int off=16; off>0; off>>=1){ gp += __shfl_xor(gp, off, 32); lp += __shfl_xor(lp, off, 32); }
    int len = (int)lp;
    int last_tag = (len==0)? START_IDX : tgt[b*L_SZ + (len-1)];
    float goldT = gp + s_trans[STOP_IDX*T_SZ + last_tag];
    if (tid==0) atomicAdd(out, (fwd - goldT) * (1.0f/B_SZ));
  }
}

extern "C" void kernel_launch(void* const* d_in, const int* in_sizes, int n_in,
                              void* d_out, int out_size, void* d_ws, size_t ws_size,
                              hipStream_t stream)
{
  const float* efeats = (const float*)d_in[0];
  const float* mask   = (const float*)d_in[1];
  const int*   tgt    = (const int*)d_in[2];
  const float* trans  = (const float*)d_in[3];
  float* out = (float*)d_out;

  const size_t needM = (size_t)NBLK_TOT * T_SZ * T_SZ * 2;   // 1 MiB
  const size_t need  = needM + (size_t)NBLK_TOT * 12;

  zero_kernel<<<dim3(1), dim3(64), 0, stream>>>(out);

  if (ws_size >= need){
    unsigned short* wsM = (unsigned short*)d_ws;
    char* p = (char*)d_ws + needM;
    int*   wsE = (int*)p;
    float* wsG = (float*)(p + (size_t)NBLK_TOT*4);
    float* wsL = (float*)(p + (size_t)NBLK_TOT*8);
    crf_chunk_kernel<<<dim3(NBLK_TOT), dim3(512), 0, stream>>>(
        efeats, mask, tgt, trans, wsM, wsE, wsG, wsL);
    crf_combine_kernel<<<dim3(B_SZ), dim3(64), 0, stream>>>(
        wsM, wsE, wsG, wsL, tgt, trans, out);
  } else {
    crf_loss_kernel<<<dim3(B_SZ), dim3(1024), 0, stream>>>(efeats, mask, tgt, trans, out);
  }
}